// Round 1
// baseline (296.255 us; speedup 1.0000x reference)
//
#include <hip/hip_runtime.h>
#include <math.h>

#define B 256
#define C 1000
#define D 128
#define QN 262144

// output layout (floats):
// [0]       output      B*C    = 256000
// [256000]  output2     B*C    = 256000
// [512000]  features    (2B+Q)*D = 33619968
// [34131968] pseudo_labels (2B+Q) = 262656
// [34394624] score_prot B*C    = 256000
// [34650624] protos     C*D    = 128000
#define OFF_FEAT   512000
#define OFF_LBL    34131968
#define OFF_SCORE  34394624
#define OFF_PROTO  34650624

// ---------------- argmax of output*partial_Y per row (first-occurrence ties) ----
__global__ __launch_bounds__(256) void argmax_kernel(
    const float* __restrict__ output,
    const float* __restrict__ partial_Y,
    int* __restrict__ labels,
    float* __restrict__ out_labels)   // d_out + OFF_LBL
{
    const int b = blockIdx.x;
    const int tid = threadIdx.x;
    const float* row = output + (size_t)b * C;
    const float* msk = partial_Y + (size_t)b * C;

    float best = -INFINITY;
    int bidx = C;  // sentinel, always replaced
    for (int c = tid; c < C; c += 256) {
        float v = row[c] * msk[c];
        if (v > best) { best = v; bidx = c; }  // strict > keeps first occurrence
    }

    __shared__ float sv[256];
    __shared__ int   si[256];
    sv[tid] = best; si[tid] = bidx;
    __syncthreads();
    for (int s = 128; s > 0; s >>= 1) {
        if (tid < s) {
            float v2 = sv[tid + s]; int i2 = si[tid + s];
            if (v2 > sv[tid] || (v2 == sv[tid] && i2 < si[tid])) {
                sv[tid] = v2; si[tid] = i2;
            }
        }
        __syncthreads();
    }
    if (tid == 0) {
        int lab = si[0];
        labels[b] = lab;
        float f = (float)lab;
        out_labels[b]     = f;
        out_labels[B + b] = f;
    }
}

// ---------------- score_prot = softmax(q @ P^T) per row -------------------------
__global__ __launch_bounds__(256) void scoreprot_kernel(
    const float* __restrict__ q,
    const float* __restrict__ protos,
    float* __restrict__ out)          // d_out + OFF_SCORE
{
    const int b = blockIdx.x;
    const int tid = threadIdx.x;

    __shared__ float qs[D];
    if (tid < D) qs[tid] = q[(size_t)b * D + tid];
    __syncthreads();

    __shared__ float logits[C];
    for (int c = tid; c < C; c += 256) {
        const float4* p4 = (const float4*)(protos + (size_t)c * D);
        const float4* q4 = (const float4*)qs;
        float acc = 0.f;
        #pragma unroll
        for (int d = 0; d < D / 4; ++d) {
            float4 pv = p4[d];
            float4 qv = q4[d];
            acc += pv.x * qv.x + pv.y * qv.y + pv.z * qv.z + pv.w * qv.w;
        }
        logits[c] = acc;
    }
    __syncthreads();

    __shared__ float red[256];
    float lm = -INFINITY;
    for (int c = tid; c < C; c += 256) lm = fmaxf(lm, logits[c]);
    red[tid] = lm;
    __syncthreads();
    for (int s = 128; s > 0; s >>= 1) {
        if (tid < s) red[tid] = fmaxf(red[tid], red[tid + s]);
        __syncthreads();
    }
    const float m = red[0];
    __syncthreads();

    float psum = 0.f;
    for (int c = tid; c < C; c += 256) {
        float e = expf(logits[c] - m);
        logits[c] = e;
        psum += e;
    }
    red[tid] = psum;
    __syncthreads();
    for (int s = 128; s > 0; s >>= 1) {
        if (tid < s) red[tid] += red[tid + s];
        __syncthreads();
    }
    const float denom = red[0];

    for (int c = tid; c < C; c += 256)
        out[(size_t)b * C + c] = logits[c] / denom;
}

// ---------------- EMA scatter (sequential-in-b per class) + L2 normalize --------
__global__ __launch_bounds__(128) void ema_kernel(
    const float* __restrict__ q,
    const float* __restrict__ protos_in,
    const int* __restrict__ labels,
    float* __restrict__ out)          // d_out + OFF_PROTO
{
    const int c = blockIdx.x;    // class row
    const int d = threadIdx.x;   // dim

    __shared__ int lab[B];
    for (int i = d; i < B; i += 128) lab[i] = labels[i];
    __syncthreads();

    float val = protos_in[(size_t)c * D + d];
    for (int b = 0; b < B; ++b) {
        if (lab[b] == c) {                       // block-uniform branch
            val = val * 0.99f + 0.01f * q[(size_t)b * D + d];
        }
    }

    __shared__ float ss[128];
    ss[d] = val * val;
    __syncthreads();
    for (int s = 64; s > 0; s >>= 1) {
        if (d < s) ss[d] += ss[d + s];
        __syncthreads();
    }
    float r = fmaxf(sqrtf(ss[0]), 1e-12f);
    out[(size_t)c * D + d] = val / r;
}

extern "C" void kernel_launch(void* const* d_in, const int* in_sizes, int n_in,
                              void* d_out, int out_size, void* d_ws, size_t ws_size,
                              hipStream_t stream) {
    const float* q            = (const float*)d_in[0];
    const float* k            = (const float*)d_in[1];
    const float* output       = (const float*)d_in[2];
    const float* output2      = (const float*)d_in[3];
    const float* partial_Y    = (const float*)d_in[4];
    const float* prototypes   = (const float*)d_in[5];
    const float* queue        = (const float*)d_in[6];
    const float* queue_pseudo = (const float*)d_in[7];

    float* out = (float*)d_out;
    int* labels = (int*)d_ws;

    // labels first (ema depends on them; same stream serializes)
    argmax_kernel<<<B, 256, 0, stream>>>(output, partial_Y, labels, out + OFF_LBL);
    ema_kernel<<<C, 128, 0, stream>>>(q, prototypes, labels, out + OFF_PROTO);
    scoreprot_kernel<<<B, 256, 0, stream>>>(q, prototypes, out + OFF_SCORE);

    // bulk copies
    hipMemcpyAsync(out,                         output,  (size_t)B * C * 4, hipMemcpyDeviceToDevice, stream);
    hipMemcpyAsync(out + B * C,                 output2, (size_t)B * C * 4, hipMemcpyDeviceToDevice, stream);
    hipMemcpyAsync(out + OFF_FEAT,              q,       (size_t)B * D * 4, hipMemcpyDeviceToDevice, stream);
    hipMemcpyAsync(out + OFF_FEAT + B * D,      k,       (size_t)B * D * 4, hipMemcpyDeviceToDevice, stream);
    hipMemcpyAsync(out + OFF_FEAT + 2 * B * D,  queue,   (size_t)QN * D * 4, hipMemcpyDeviceToDevice, stream);
    hipMemcpyAsync(out + OFF_LBL + 2 * B,       queue_pseudo, (size_t)QN * 4, hipMemcpyDeviceToDevice, stream);
}